// Round 2
// baseline (264.637 us; speedup 1.0000x reference)
//
#include <hip/hip_runtime.h>
#include <hip/hip_bf16.h>

#define VNUM 6890
#define BNUM 512
#define NJ 24

// ws layout (floats):
//   js  [24*33]     = 792      (JS[j,c,s] s<10, JT at s=10)
//   lw  [512*208]   = 106496   (lrotmin padded: [207]=0)
//   gp  [512*24*12] = 147456   (G' 3x4 row-major per (b,j))
#define WS_JS 0
#define WS_LW 792
#define WS_GP (792 + 512*208)

#define RES_ELEMS (512*6890*3)

// ---------------- Kernel A: JS/JT = reduce_v Jr[j,v] * {shapedirs, v_template}
__global__ __launch_bounds__(256) void ka_kernel(const float* __restrict__ Jr,
                                                 const float* __restrict__ sd,
                                                 const float* __restrict__ vt,
                                                 float* __restrict__ js) {
    int j = blockIdx.x;
    int tid = threadIdx.x;
    float acc[33];
#pragma unroll
    for (int k = 0; k < 33; ++k) acc[k] = 0.f;
    for (int v = tid; v < VNUM; v += 256) {
        float q = Jr[j * VNUM + v];
#pragma unroll
        for (int c = 0; c < 3; ++c) {
#pragma unroll
            for (int s = 0; s < 10; ++s)
                acc[c * 11 + s] += q * sd[v * 30 + c * 10 + s];
            acc[c * 11 + 10] += q * vt[v * 3 + c];
        }
    }
#pragma unroll
    for (int k = 0; k < 33; ++k) {
        float a = acc[k];
#pragma unroll
        for (int off = 32; off >= 1; off >>= 1) a += __shfl_xor(a, off);
        acc[k] = a;
    }
    __shared__ float red[4][33];
    int lane = tid & 63, wid = tid >> 6;
    if (lane == 0) {
#pragma unroll
        for (int k = 0; k < 33; ++k) red[wid][k] = acc[k];
    }
    __syncthreads();
    if (tid < 33)
        js[j * 33 + tid] = red[0][tid] + red[1][tid] + red[2][tid] + red[3][tid];
}

// ---------------- Kernel B: per-batch rodrigues, lrotmin (padded to 208), J, chain, G'
__global__ __launch_bounds__(64) void kb_kernel(const float* __restrict__ pose,
                                                const float* __restrict__ betas,
                                                const float* __restrict__ js,
                                                float* __restrict__ lw,
                                                float* __restrict__ gp) {
    int b = blockIdx.x;
    int t = threadIdx.x;
    __shared__ float Rl[24][9];
    __shared__ float Jl[24][3];
    __shared__ float Gl[24][12];

    if (t < 24) {
        float x = pose[b * 72 + t * 3 + 0];
        float y = pose[b * 72 + t * 3 + 1];
        float z = pose[b * 72 + t * 3 + 2];
        float th = sqrtf(x * x + y * y + z * z) + 1e-8f;
        float rx = x / th, ry = y / th, rz = z / th;
        float cs = cosf(th), sn = sinf(th), mc = 1.f - cs;
        float R[9];
        R[0] = cs + mc * rx * rx;      R[1] = mc * rx * ry - sn * rz; R[2] = mc * rx * rz + sn * ry;
        R[3] = mc * ry * rx + sn * rz; R[4] = cs + mc * ry * ry;      R[5] = mc * ry * rz - sn * rx;
        R[6] = mc * rz * rx - sn * ry; R[7] = mc * rz * ry + sn * rx; R[8] = cs + mc * rz * rz;
#pragma unroll
        for (int k = 0; k < 9; ++k) Rl[t][k] = R[k];
        if (t >= 1) {
#pragma unroll
            for (int k = 0; k < 9; ++k)
                lw[(size_t)b * 208 + (t - 1) * 9 + k] = R[k] - ((k == 0 || k == 4 || k == 8) ? 1.f : 0.f);
        }
#pragma unroll
        for (int c = 0; c < 3; ++c) {
            float a = js[(t * 3 + c) * 11 + 10];
#pragma unroll
            for (int s = 0; s < 10; ++s) a += betas[b * 10 + s] * js[(t * 3 + c) * 11 + s];
            Jl[t][c] = a;
        }
    }
    if (t == 24) lw[(size_t)b * 208 + 207] = 0.f;  // zero pad
    __syncthreads();

    if (t < 12) {
        int x = t >> 2, yy = t & 3;
        Gl[0][t] = (yy < 3) ? Rl[0][x * 3 + yy] : Jl[0][x];
    }
    __syncthreads();

    const int par[24] = {-1, 0, 0, 0, 1, 2, 3, 4, 5, 6, 7, 8, 9, 9, 9, 12, 13, 14, 16, 17, 18, 19, 20, 21};
#pragma unroll
    for (int i = 1; i < 24; ++i) {
        if (t < 12) {
            int x = t >> 2, yy = t & 3;
            int p = par[i];
            float a0, a1, a2, add;
            if (yy < 3) {
                a0 = Rl[i][0 * 3 + yy]; a1 = Rl[i][1 * 3 + yy]; a2 = Rl[i][2 * 3 + yy]; add = 0.f;
            } else {
                a0 = Jl[i][0] - Jl[p][0]; a1 = Jl[i][1] - Jl[p][1]; a2 = Jl[i][2] - Jl[p][2];
                add = Gl[p][x * 4 + 3];
            }
            Gl[i][t] = Gl[p][x * 4 + 0] * a0 + Gl[p][x * 4 + 1] * a1 + Gl[p][x * 4 + 2] * a2 + add;
        }
        __syncthreads();
    }

    if (t < 24) {
#pragma unroll
        for (int x = 0; x < 3; ++x) {
            float tx = Gl[t][x * 4 + 0] * Jl[t][0] + Gl[t][x * 4 + 1] * Jl[t][1] + Gl[t][x * 4 + 2] * Jl[t][2];
#pragma unroll
            for (int yy = 0; yy < 3; ++yy)
                gp[(size_t)b * 288 + t * 12 + x * 4 + yy] = Gl[t][x * 4 + yy];
            gp[(size_t)b * 288 + t * 12 + x * 4 + 3] = Gl[t][x * 4 + 3] - tx;
        }
    }
}

// ---------------- Kernel C: fused shape-blend + pose-blend + skinning
// grid (108, 16), block 256. lane = vloc (64 v/block), wave handles 8 batches (32/block).
// LDS pd: [48 rows = (c*16+p)][65] (stride 65 -> conflict-free reads AND spread writes).
// 13 chunks of 16 p (lw zero-padded to 208). T14 async-stage: load regs -> compute -> bar -> write -> bar.
__global__ __launch_bounds__(256) void kc_kernel(const float* __restrict__ posedirs,
                                                 const float* __restrict__ lw,
                                                 const float* __restrict__ gpb,
                                                 const float* __restrict__ betas,
                                                 const float* __restrict__ sdirs,
                                                 const float* __restrict__ vt,
                                                 const float* __restrict__ trans,
                                                 const float* __restrict__ wgts,
                                                 float* __restrict__ out) {
    __shared__ float pd[48 * 65];
    __shared__ float wl[64 * 25];

    int tid = threadIdx.x;
    int lane = tid & 63;
    int wid = __builtin_amdgcn_readfirstlane(tid >> 6);
    int v0 = blockIdx.x * 64;
    int v = v0 + lane;
    int vc = min(v, VNUM - 1);
    int b0 = __builtin_amdgcn_readfirstlane(blockIdx.y * 32 + wid * 8);

    // stage weights tile once
    for (int t = tid; t < 64 * 24; t += 256) {
        int vv = t / 24, j = t - vv * 24;
        wl[vv * 25 + j] = wgts[(size_t)min(v0 + vv, VNUM - 1) * 24 + j];
    }

    // loop-invariant staging decode: thread handles 3 quads; Q = tid + 256*s
    // Q -> (vq = Q/12, c = (Q%12)>>2, q = (Q%12)&3); global row slice + clamp limit
    const float* rowp[3];
    int lim[3];
    int wbase[3];
#pragma unroll
    for (int s = 0; s < 3; ++s) {
        int Q = tid + 256 * s;
        int vq = Q / 12;
        int rem = Q - vq * 12;
        int c = rem >> 2, q = rem & 3;
        int offb = c * 207 + q * 4;
        rowp[s] = posedirs + (size_t)min(v0 + vq, VNUM - 1) * 621 + offb;
        lim[s] = 620 - offb;                    // idx within row must be <= 620
        wbase[s] = (c * 16 + q * 4) * 65 + vq;  // LDS float index base
    }

    float tmp[12];
    // prefetch chunk 0
#pragma unroll
    for (int s = 0; s < 3; ++s)
#pragma unroll
        for (int k = 0; k < 4; ++k)
            tmp[s * 4 + k] = rowp[s][min(0 + k, lim[s])];

    // per-lane v_template / shapedirs; acc init with v_shaped (betas -> s_load)
    float vtl[3];
#pragma unroll
    for (int c = 0; c < 3; ++c) vtl[c] = vt[vc * 3 + c];
    float sdl[30];
#pragma unroll
    for (int k = 0; k < 30; ++k) sdl[k] = sdirs[vc * 30 + k];
    float acc[8][3];
#pragma unroll
    for (int i = 0; i < 8; ++i) {
#pragma unroll
        for (int c = 0; c < 3; ++c) {
            float a = vtl[c];
#pragma unroll
            for (int s = 0; s < 10; ++s) a += betas[(b0 + i) * 10 + s] * sdl[c * 10 + s];
            acc[i][c] = a;
        }
    }

    __syncthreads();  // wl + nothing reads pd yet
#pragma unroll
    for (int s = 0; s < 3; ++s)
#pragma unroll
        for (int k = 0; k < 4; ++k)
            pd[wbase[s] + k * 65] = tmp[s * 4 + k];
    __syncthreads();

    for (int ch = 0; ch < 13; ++ch) {
        int pc = ch * 16;
        float tmp2[12];
        if (ch < 12) {
            int pn = pc + 16;
#pragma unroll
            for (int s = 0; s < 3; ++s)
#pragma unroll
                for (int k = 0; k < 4; ++k)
                    tmp2[s * 4 + k] = rowp[s][min(pn + k, lim[s])];
        }
        // compute chunk ch: 16 p, lw via uniform float4 (s_load_dwordx4)
#pragma unroll
        for (int p4 = 0; p4 < 4; ++p4) {
            float4 lv[8];
#pragma unroll
            for (int i = 0; i < 8; ++i)
                lv[i] = *(const float4*)&lw[(size_t)(b0 + i) * 208 + pc + p4 * 4];
#pragma unroll
            for (int kk = 0; kk < 4; ++kk) {
                int p = p4 * 4 + kk;
                float e0 = pd[p * 65 + lane];
                float e1 = pd[(16 + p) * 65 + lane];
                float e2 = pd[(32 + p) * 65 + lane];
#pragma unroll
                for (int i = 0; i < 8; ++i) {
                    float lr = (&lv[i].x)[kk];
                    acc[i][0] = fmaf(lr, e0, acc[i][0]);
                    acc[i][1] = fmaf(lr, e1, acc[i][1]);
                    acc[i][2] = fmaf(lr, e2, acc[i][2]);
                }
            }
        }
        if (ch < 12) {
            __syncthreads();
#pragma unroll
            for (int s = 0; s < 3; ++s)
#pragma unroll
                for (int k = 0; k < 4; ++k)
                    pd[wbase[s] + k * 65] = tmp2[s * 4 + k];
            __syncthreads();
        }
    }

    // skinning: T = sum_j w[v,j] * G'[b,j]; out = T.[vp,1] + trans
    float wg[24];
#pragma unroll
    for (int j = 0; j < 24; ++j) wg[j] = wl[lane * 25 + j];

#pragma unroll 2
    for (int i = 0; i < 8; ++i) {
        int b = b0 + i;
        const float* g = gpb + (size_t)b * 288;
        float T[12];
#pragma unroll
        for (int r = 0; r < 12; ++r) T[r] = 0.f;
#pragma unroll
        for (int j = 0; j < 24; ++j) {
            float4 g0 = *(const float4*)&g[j * 12 + 0];
            float4 g1 = *(const float4*)&g[j * 12 + 4];
            float4 g2 = *(const float4*)&g[j * 12 + 8];
            float w_ = wg[j];
            T[0] += w_ * g0.x; T[1] += w_ * g0.y; T[2] += w_ * g0.z; T[3] += w_ * g0.w;
            T[4] += w_ * g1.x; T[5] += w_ * g1.y; T[6] += w_ * g1.z; T[7] += w_ * g1.w;
            T[8] += w_ * g2.x; T[9] += w_ * g2.y; T[10] += w_ * g2.z; T[11] += w_ * g2.w;
        }
        float vx = acc[i][0], vy = acc[i][1], vz = acc[i][2];
        float o0 = T[0] * vx + T[1] * vy + T[2] * vz + T[3] + trans[b * 3 + 0];
        float o1 = T[4] * vx + T[5] * vy + T[6] * vz + T[7] + trans[b * 3 + 1];
        float o2 = T[8] * vx + T[9] * vy + T[10] * vz + T[11] + trans[b * 3 + 2];
        if (v < VNUM) {
            float* o = out + ((size_t)b * VNUM + v) * 3;
            o[0] = o0; o[1] = o1; o[2] = o2;
        }
    }
}

// ---------------- Kernel D: joints[b,j,c] = sum_v jr2[j,v] * result[b,v,c]
__global__ __launch_bounds__(256) void kd_kernel(const float* __restrict__ res,
                                                 const float* __restrict__ jr2,
                                                 float* __restrict__ joints) {
    int b = blockIdx.x;
    int tid = threadIdx.x;
    float acc[24][3];
#pragma unroll
    for (int j = 0; j < 24; ++j)
#pragma unroll
        for (int c = 0; c < 3; ++c) acc[j][c] = 0.f;

    const float* rb = res + (size_t)b * VNUM * 3;
    for (int v = tid; v < VNUM; v += 256) {
        float r0 = rb[v * 3 + 0];
        float r1 = rb[v * 3 + 1];
        float r2 = rb[v * 3 + 2];
#pragma unroll
        for (int j = 0; j < 24; ++j) {
            float q = jr2[(size_t)j * VNUM + v];
            acc[j][0] += q * r0;
            acc[j][1] += q * r1;
            acc[j][2] += q * r2;
        }
    }
#pragma unroll
    for (int j = 0; j < 24; ++j)
#pragma unroll
        for (int c = 0; c < 3; ++c) {
            float a = acc[j][c];
#pragma unroll
            for (int off = 32; off >= 1; off >>= 1) a += __shfl_xor(a, off);
            acc[j][c] = a;
        }
    __shared__ float red[4][72];
    int lane = tid & 63, wid = tid >> 6;
    if (lane == 0) {
#pragma unroll
        for (int j = 0; j < 24; ++j)
#pragma unroll
            for (int c = 0; c < 3; ++c) red[wid][j * 3 + c] = acc[j][c];
    }
    __syncthreads();
    if (tid < 72)
        joints[(size_t)b * 72 + tid] = red[0][tid] + red[1][tid] + red[2][tid] + red[3][tid];
}

extern "C" void kernel_launch(void* const* d_in, const int* in_sizes, int n_in,
                              void* d_out, int out_size, void* d_ws, size_t ws_size,
                              hipStream_t stream) {
    const float* betas = (const float*)d_in[0];
    const float* pose = (const float*)d_in[1];
    const float* trans = (const float*)d_in[2];
    const float* v_template = (const float*)d_in[3];
    const float* shapedirs = (const float*)d_in[4];
    const float* posedirs = (const float*)d_in[5];
    const float* J_regressor = (const float*)d_in[6];
    const float* joint_regressor = (const float*)d_in[7];
    const float* weights = (const float*)d_in[8];
    float* out = (float*)d_out;

    float* wsf = (float*)d_ws;  // ~1.02 MB
    float* js = wsf + WS_JS;
    float* lw = wsf + WS_LW;
    float* gp = wsf + WS_GP;

    ka_kernel<<<24, 256, 0, stream>>>(J_regressor, shapedirs, v_template, js);
    kb_kernel<<<512, 64, 0, stream>>>(pose, betas, js, lw, gp);
    kc_kernel<<<dim3(108, 16), 256, 0, stream>>>(posedirs, lw, gp, betas, shapedirs,
                                                 v_template, trans, weights, out);
    kd_kernel<<<512, 256, 0, stream>>>(out, joint_regressor, out + RES_ELEMS);
}

// Round 3
// 125.539 us; speedup vs baseline: 2.1080x; 2.1080x over previous
//
#include <hip/hip_runtime.h>
#include <hip/hip_bf16.h>

#define VNUM 6890
#define VPAD 6912
#define BNUM 512
#define NJ 24

typedef short bf16x8 __attribute__((ext_vector_type(8)));
typedef float f32x4 __attribute__((ext_vector_type(4)));

__device__ __forceinline__ short f2bf(float x) {
    union { float f; unsigned u; } v; v.f = x;
    unsigned r = v.u + 0x7fff + ((v.u >> 16) & 1);
    return (short)(r >> 16);
}

// ws layout (float offsets, all 16B-aligned):
//   js   [24*33]              = 792    fp32
//   lwX  at 800    : 512*224 bf16      (lrotmin|betas|1|0 pad)   57344 floats
//   G'A  at 58144  : 12*512*32 bf16    (skinning A, trans folded) 98304 floats
//   Wt   at 156448 : 6912*32 bf16      (weights, j-padded)       110592 floats
//   PB   at 267040 : 3*6912*224 bf16   (posedirs|shapedirs|vt|0) 2322432 floats
#define WS_JS 0
#define WS_LWX 800
#define WS_GA 58144
#define WS_WT 156448
#define WS_PB 267040

#define RES_ELEMS (512 * 6890 * 3)

// ---------------- Kernel A: JS/JT = reduce_v Jr[j,v] * {shapedirs, v_template}
__global__ __launch_bounds__(256) void ka_kernel(const float* __restrict__ Jr,
                                                 const float* __restrict__ sd,
                                                 const float* __restrict__ vt,
                                                 float* __restrict__ js) {
    int j = blockIdx.x;
    int tid = threadIdx.x;
    float acc[33];
#pragma unroll
    for (int k = 0; k < 33; ++k) acc[k] = 0.f;
    for (int v = tid; v < VNUM; v += 256) {
        float q = Jr[j * VNUM + v];
#pragma unroll
        for (int c = 0; c < 3; ++c) {
#pragma unroll
            for (int s = 0; s < 10; ++s)
                acc[c * 11 + s] += q * sd[v * 30 + c * 10 + s];
            acc[c * 11 + 10] += q * vt[v * 3 + c];
        }
    }
#pragma unroll
    for (int k = 0; k < 33; ++k) {
        float a = acc[k];
#pragma unroll
        for (int off = 32; off >= 1; off >>= 1) a += __shfl_xor(a, off);
        acc[k] = a;
    }
    __shared__ float red[4][33];
    int lane = tid & 63, wid = tid >> 6;
    if (lane == 0) {
#pragma unroll
        for (int k = 0; k < 33; ++k) red[wid][k] = acc[k];
    }
    __syncthreads();
    if (tid < 33)
        js[j * 33 + tid] = red[0][tid] + red[1][tid] + red[2][tid] + red[3][tid];
}

// ---------------- Kernel B: rodrigues, lwX (bf16), J, chain, G'A (bf16, trans folded)
__global__ __launch_bounds__(64) void kb_kernel(const float* __restrict__ pose,
                                                const float* __restrict__ betas,
                                                const float* __restrict__ trans,
                                                const float* __restrict__ js,
                                                short* __restrict__ lwX,
                                                short* __restrict__ ga) {
    int b = blockIdx.x;
    int t = threadIdx.x;
    __shared__ float Rl[24][9];
    __shared__ float Jl[24][3];
    __shared__ float Gl[24][12];

    if (t < 24) {
        float x = pose[b * 72 + t * 3 + 0];
        float y = pose[b * 72 + t * 3 + 1];
        float z = pose[b * 72 + t * 3 + 2];
        float th = sqrtf(x * x + y * y + z * z) + 1e-8f;
        float rx = x / th, ry = y / th, rz = z / th;
        float cs = cosf(th), sn = sinf(th), mc = 1.f - cs;
        float R[9];
        R[0] = cs + mc * rx * rx;      R[1] = mc * rx * ry - sn * rz; R[2] = mc * rx * rz + sn * ry;
        R[3] = mc * ry * rx + sn * rz; R[4] = cs + mc * ry * ry;      R[5] = mc * ry * rz - sn * rx;
        R[6] = mc * rz * rx - sn * ry; R[7] = mc * rz * ry + sn * rx; R[8] = cs + mc * rz * rz;
#pragma unroll
        for (int k = 0; k < 9; ++k) Rl[t][k] = R[k];
        if (t >= 1) {
#pragma unroll
            for (int k = 0; k < 9; ++k)
                lwX[b * 224 + (t - 1) * 9 + k] =
                    f2bf(R[k] - ((k == 0 || k == 4 || k == 8) ? 1.f : 0.f));
        }
#pragma unroll
        for (int c = 0; c < 3; ++c) {
            float a = js[(t * 3 + c) * 11 + 10];
#pragma unroll
            for (int s = 0; s < 10; ++s) a += betas[b * 10 + s] * js[(t * 3 + c) * 11 + s];
            Jl[t][c] = a;
        }
    } else if (t >= 32 && t < 42) {
        lwX[b * 224 + 207 + (t - 32)] = f2bf(betas[b * 10 + (t - 32)]);
    } else if (t == 42) {
        lwX[b * 224 + 217] = f2bf(1.f);
    } else if (t >= 43 && t < 49) {
        lwX[b * 224 + 218 + (t - 43)] = 0;
    }
    __syncthreads();

    if (t < 12) {
        int x = t >> 2, yy = t & 3;
        Gl[0][t] = (yy < 3) ? Rl[0][x * 3 + yy] : Jl[0][x];
    }
    __syncthreads();

    const int par[24] = {-1, 0, 0, 0, 1, 2, 3, 4, 5, 6, 7, 8, 9, 9, 9, 12, 13, 14, 16, 17, 18, 19, 20, 21};
#pragma unroll
    for (int i = 1; i < 24; ++i) {
        if (t < 12) {
            int x = t >> 2, yy = t & 3;
            int p = par[i];
            float a0, a1, a2, add;
            if (yy < 3) {
                a0 = Rl[i][0 * 3 + yy]; a1 = Rl[i][1 * 3 + yy]; a2 = Rl[i][2 * 3 + yy]; add = 0.f;
            } else {
                a0 = Jl[i][0] - Jl[p][0]; a1 = Jl[i][1] - Jl[p][1]; a2 = Jl[i][2] - Jl[p][2];
                add = Gl[p][x * 4 + 3];
            }
            Gl[i][t] = Gl[p][x * 4 + 0] * a0 + Gl[p][x * 4 + 1] * a1 + Gl[p][x * 4 + 2] * a2 + add;
        }
        __syncthreads();
    }

    // G'A[r][b][j], r = x*4+y; translation adjusted (−G·J) and trans folded (Σ_j w = 1)
    if (t < 24) {
#pragma unroll
        for (int x = 0; x < 3; ++x) {
            float tx = Gl[t][x * 4 + 0] * Jl[t][0] + Gl[t][x * 4 + 1] * Jl[t][1] + Gl[t][x * 4 + 2] * Jl[t][2];
#pragma unroll
            for (int yy = 0; yy < 3; ++yy)
                ga[(x * 4 + yy) * (512 * 32) + b * 32 + t] = f2bf(Gl[t][x * 4 + yy]);
            ga[(x * 4 + 3) * (512 * 32) + b * 32 + t] =
                f2bf(Gl[t][x * 4 + 3] - tx + trans[b * 3 + x]);
        }
    } else if (t < 32) {
#pragma unroll
        for (int r = 0; r < 12; ++r) ga[r * (512 * 32) + b * 32 + t] = 0;
    }
}

// ---------------- Kernel PE: PB[c][v][224] bf16 = posedirs | shapedirs | vt | 0
__global__ __launch_bounds__(256) void pe_kernel(const float* __restrict__ pd,
                                                 const float* __restrict__ sd,
                                                 const float* __restrict__ vt,
                                                 short* __restrict__ pb) {
    int v0 = blockIdx.x * 32;
    int c = blockIdx.y;
    int t = threadIdx.x;
    int vloc = t >> 3, sub = t & 7;
    int v = v0 + vloc;
    short* dst = pb + ((size_t)c * VPAD + v) * 224;
    if (v < VNUM) {
        const float* pr = pd + (size_t)v * 621 + c * 207;
        const float* sr = sd + (size_t)v * 30 + c * 10;
        float vtv = vt[v * 3 + c];
#pragma unroll
        for (int i = 0; i < 28; ++i) {
            int k = sub + i * 8;
            float val;
            if (k < 207) val = pr[k];
            else if (k < 217) val = sr[k - 207];
            else if (k == 217) val = vtv;
            else val = 0.f;
            dst[k] = f2bf(val);
        }
    } else {
#pragma unroll
        for (int i = 0; i < 28; ++i) dst[sub + i * 8] = 0;
    }
}

// ---------------- Kernel WP: Wt[v][32] bf16 = weights row, j-padded
__global__ __launch_bounds__(256) void wp_kernel(const float* __restrict__ w,
                                                 short* __restrict__ wt) {
    int v = blockIdx.x * 256 + threadIdx.x;
    if (v >= VPAD) return;
    short* dst = wt + (size_t)v * 32;
    if (v < VNUM) {
#pragma unroll
        for (int j = 0; j < 24; ++j) dst[j] = f2bf(w[(size_t)v * 24 + j]);
#pragma unroll
        for (int j = 24; j < 32; ++j) dst[j] = 0;
    } else {
#pragma unroll
        for (int j = 0; j < 32; ++j) dst[j] = 0;
    }
}

// ---------------- Kernel M: MFMA pose+shape blend, MFMA skinning, in-register apply
// grid (16, 54): bx -> 32 batches, by -> 128 vertices (4 waves x 32 v)
__global__ __launch_bounds__(256) void km_kernel(const short* __restrict__ lwX,
                                                 const short* __restrict__ pb,
                                                 const short* __restrict__ ga,
                                                 const short* __restrict__ wt,
                                                 float* __restrict__ out) {
    int tid = threadIdx.x;
    int lane = tid & 63;
    int wid = tid >> 6;
    int row = lane & 15;
    int kq = lane >> 4;
    int b0 = blockIdx.x * 32;
    int v0 = blockIdx.y * 128 + wid * 32;

    f32x4 vp[2][2][3];  // [mrep][vb][c]
#pragma unroll
    for (int m = 0; m < 2; ++m)
#pragma unroll
        for (int vb = 0; vb < 2; ++vb)
#pragma unroll
            for (int c = 0; c < 3; ++c) vp[m][vb][c] = (f32x4){0.f, 0.f, 0.f, 0.f};

    // Phase 1: vp[b][v,c] = sum_k lwX[b][k] * PB[c][v][k], K = 224 (7 steps)
    const short* arow0 = lwX + (b0 + row) * 224 + kq * 8;
    const short* arow1 = arow0 + 16 * 224;
#pragma unroll
    for (int ks = 0; ks < 7; ++ks) {
        bf16x8 a0 = *(const bf16x8*)(arow0 + ks * 32);
        bf16x8 a1 = *(const bf16x8*)(arow1 + ks * 32);
#pragma unroll
        for (int vb = 0; vb < 2; ++vb) {
#pragma unroll
            for (int c = 0; c < 3; ++c) {
                bf16x8 bf = *(const bf16x8*)(pb + ((size_t)c * VPAD + v0 + vb * 16 + row) * 224 +
                                             ks * 32 + kq * 8);
                vp[0][vb][c] = __builtin_amdgcn_mfma_f32_16x16x32_bf16(a0, bf, vp[0][vb][c], 0, 0, 0);
                vp[1][vb][c] = __builtin_amdgcn_mfma_f32_16x16x32_bf16(a1, bf, vp[1][vb][c], 0, 0, 0);
            }
        }
    }

    // Phase 2: T_r[b][v] = sum_j G'A[r][b][j] * Wt[v][j]; res[x] = T_{x4+3} + sum_y T_{x4+y}*vp[y]
    bf16x8 wfrag[2];
#pragma unroll
    for (int vb = 0; vb < 2; ++vb)
        wfrag[vb] = *(const bf16x8*)(wt + (size_t)(v0 + vb * 16 + row) * 32 + kq * 8);

    const f32x4 zero4 = {0.f, 0.f, 0.f, 0.f};
    int brow = (lane >> 4) * 4;

#pragma unroll
    for (int x = 0; x < 3; ++x) {
        f32x4 res[2][2];
        // y = 3 (translation) first: res = T
        {
            int r = x * 4 + 3;
            bf16x8 g0 = *(const bf16x8*)(ga + ((size_t)r * 512 + b0 + row) * 32 + kq * 8);
            bf16x8 g1 = *(const bf16x8*)(ga + ((size_t)r * 512 + b0 + 16 + row) * 32 + kq * 8);
#pragma unroll
            for (int vb = 0; vb < 2; ++vb) {
                res[0][vb] = __builtin_amdgcn_mfma_f32_16x16x32_bf16(g0, wfrag[vb], zero4, 0, 0, 0);
                res[1][vb] = __builtin_amdgcn_mfma_f32_16x16x32_bf16(g1, wfrag[vb], zero4, 0, 0, 0);
            }
        }
#pragma unroll
        for (int y = 0; y < 3; ++y) {
            int r = x * 4 + y;
            bf16x8 g0 = *(const bf16x8*)(ga + ((size_t)r * 512 + b0 + row) * 32 + kq * 8);
            bf16x8 g1 = *(const bf16x8*)(ga + ((size_t)r * 512 + b0 + 16 + row) * 32 + kq * 8);
#pragma unroll
            for (int vb = 0; vb < 2; ++vb) {
                f32x4 t0 = __builtin_amdgcn_mfma_f32_16x16x32_bf16(g0, wfrag[vb], zero4, 0, 0, 0);
                f32x4 t1 = __builtin_amdgcn_mfma_f32_16x16x32_bf16(g1, wfrag[vb], zero4, 0, 0, 0);
#pragma unroll
                for (int reg = 0; reg < 4; ++reg) {
                    res[0][vb][reg] += t0[reg] * vp[0][vb][y][reg];
                    res[1][vb][reg] += t1[reg] * vp[1][vb][y][reg];
                }
            }
        }
        // store component x
#pragma unroll
        for (int m = 0; m < 2; ++m) {
#pragma unroll
            for (int vb = 0; vb < 2; ++vb) {
                int v = v0 + vb * 16 + row;
                if (v < VNUM) {
#pragma unroll
                    for (int reg = 0; reg < 4; ++reg) {
                        int b = b0 + m * 16 + brow + reg;
                        out[((size_t)b * VNUM + v) * 3 + x] = res[m][vb][reg];
                    }
                }
            }
        }
    }
}

// ---------------- Kernel D: joints[b,j,c] = sum_v jr2[j,v] * result[b,v,c]
__global__ __launch_bounds__(256) void kd_kernel(const float* __restrict__ res,
                                                 const float* __restrict__ jr2,
                                                 float* __restrict__ joints) {
    int b = blockIdx.x;
    int tid = threadIdx.x;
    float acc[24][3];
#pragma unroll
    for (int j = 0; j < 24; ++j)
#pragma unroll
        for (int c = 0; c < 3; ++c) acc[j][c] = 0.f;

    const float* rb = res + (size_t)b * VNUM * 3;
    for (int v = tid; v < VNUM; v += 256) {
        float r0 = rb[v * 3 + 0];
        float r1 = rb[v * 3 + 1];
        float r2 = rb[v * 3 + 2];
#pragma unroll
        for (int j = 0; j < 24; ++j) {
            float q = jr2[(size_t)j * VNUM + v];
            acc[j][0] += q * r0;
            acc[j][1] += q * r1;
            acc[j][2] += q * r2;
        }
    }
#pragma unroll
    for (int j = 0; j < 24; ++j)
#pragma unroll
        for (int c = 0; c < 3; ++c) {
            float a = acc[j][c];
#pragma unroll
            for (int off = 32; off >= 1; off >>= 1) a += __shfl_xor(a, off);
            acc[j][c] = a;
        }
    __shared__ float red[4][72];
    int lane = tid & 63, wid = tid >> 6;
    if (lane == 0) {
#pragma unroll
        for (int j = 0; j < 24; ++j)
#pragma unroll
            for (int c = 0; c < 3; ++c) red[wid][j * 3 + c] = acc[j][c];
    }
    __syncthreads();
    if (tid < 72)
        joints[(size_t)b * 72 + tid] = red[0][tid] + red[1][tid] + red[2][tid] + red[3][tid];
}

extern "C" void kernel_launch(void* const* d_in, const int* in_sizes, int n_in,
                              void* d_out, int out_size, void* d_ws, size_t ws_size,
                              hipStream_t stream) {
    const float* betas = (const float*)d_in[0];
    const float* pose = (const float*)d_in[1];
    const float* trans = (const float*)d_in[2];
    const float* v_template = (const float*)d_in[3];
    const float* shapedirs = (const float*)d_in[4];
    const float* posedirs = (const float*)d_in[5];
    const float* J_regressor = (const float*)d_in[6];
    const float* joint_regressor = (const float*)d_in[7];
    const float* weights = (const float*)d_in[8];
    float* out = (float*)d_out;

    float* wsf = (float*)d_ws;  // needs ~10.4 MB
    float* js = wsf + WS_JS;
    short* lwX = (short*)(wsf + WS_LWX);
    short* ga = (short*)(wsf + WS_GA);
    short* wt = (short*)(wsf + WS_WT);
    short* pb = (short*)(wsf + WS_PB);

    ka_kernel<<<24, 256, 0, stream>>>(J_regressor, shapedirs, v_template, js);
    pe_kernel<<<dim3(216, 3), 256, 0, stream>>>(posedirs, shapedirs, v_template, pb);
    wp_kernel<<<27, 256, 0, stream>>>(weights, wt);
    kb_kernel<<<512, 64, 0, stream>>>(pose, betas, trans, js, lwX, ga);
    km_kernel<<<dim3(16, 54), 256, 0, stream>>>(lwX, pb, ga, wt, out);
    kd_kernel<<<512, 256, 0, stream>>>(out, joint_regressor, out + RES_ELEMS);
}

// Round 8
// 106.338 us; speedup vs baseline: 2.4886x; 1.1806x over previous
//
#include <hip/hip_runtime.h>
#include <hip/hip_bf16.h>

#define VNUM 6890
#define VPAD 6912
#define BNUM 512
#define NJ 24

typedef short bf16x8 __attribute__((ext_vector_type(8)));
typedef float f32x4 __attribute__((ext_vector_type(4)));

__device__ __forceinline__ short f2bf(float x) {
    union { float f; unsigned u; } v; v.f = x;
    unsigned r = v.u + 0x7fff + ((v.u >> 16) & 1);
    return (short)(r >> 16);
}

// ws layout (float offsets; R3's verified layout):
//   js   at 0      : 792 fp32
//   lwX  at 800    : 512*224 bf16   = 57344 floats  -> ends 58144
//   ga   at 58144  : 12*512*32 bf16 = 98304 floats  -> ends 156448
//   wt   at 156448 : 6912*32 bf16   = 110592 floats -> ends 267040
//   pb   at 267040 : 3*6912*224 bf16 = 2322432 floats -> ends 2589472
//   part ALIASES pb start (6336 fp32; ka -> ka2 read BEFORE pe overwrites; same stream)
#define WS_JS 0
#define WS_LWX 800
#define WS_GA 58144
#define WS_WT 156448
#define WS_PB 267040
#define WS_PART 267040

#define RES_ELEMS (512 * 6890 * 3)

// ---------------- Kernel A (split): partial JS/JT over V-chunks
__global__ __launch_bounds__(256) void ka_kernel(const float* __restrict__ Jr,
                                                 const float* __restrict__ sd,
                                                 const float* __restrict__ vt,
                                                 float* __restrict__ part) {
    int j = blockIdx.x;
    int ch = blockIdx.y;
    int tid = threadIdx.x;
    int vbeg = ch * 864;
    int vend = min(vbeg + 864, VNUM);
    float acc[33];
#pragma unroll
    for (int k = 0; k < 33; ++k) acc[k] = 0.f;
    for (int v = vbeg + tid; v < vend; v += 256) {
        float q = Jr[j * VNUM + v];
#pragma unroll
        for (int c = 0; c < 3; ++c) {
#pragma unroll
            for (int s = 0; s < 10; ++s)
                acc[c * 11 + s] += q * sd[v * 30 + c * 10 + s];
            acc[c * 11 + 10] += q * vt[v * 3 + c];
        }
    }
#pragma unroll
    for (int k = 0; k < 33; ++k) {
        float a = acc[k];
#pragma unroll
        for (int off = 32; off >= 1; off >>= 1) a += __shfl_xor(a, off);
        acc[k] = a;
    }
    __shared__ float red[4][33];
    int lane = tid & 63, wid = tid >> 6;
    if (lane == 0) {
#pragma unroll
        for (int k = 0; k < 33; ++k) red[wid][k] = acc[k];
    }
    __syncthreads();
    if (tid < 33)
        part[(j * 8 + ch) * 33 + tid] = red[0][tid] + red[1][tid] + red[2][tid] + red[3][tid];
}

// ---------------- Kernel A2: sum 8 chunks
__global__ __launch_bounds__(64) void ka2_kernel(const float* __restrict__ part,
                                                 float* __restrict__ js) {
    int j = blockIdx.x;
    int t = threadIdx.x;
    if (t < 33) {
        float a = 0.f;
#pragma unroll
        for (int ch = 0; ch < 8; ++ch) a += part[(j * 8 + ch) * 33 + t];
        js[j * 33 + t] = a;
    }
}

// ---------------- Kernel B: rodrigues, lwX (bf16), J, chain, G'A (bf16, trans folded)
__global__ __launch_bounds__(64) void kb_kernel(const float* __restrict__ pose,
                                                const float* __restrict__ betas,
                                                const float* __restrict__ trans,
                                                const float* __restrict__ js,
                                                short* __restrict__ lwX,
                                                short* __restrict__ ga) {
    int b = blockIdx.x;
    int t = threadIdx.x;
    __shared__ float Rl[24][9];
    __shared__ float Jl[24][3];
    __shared__ float Gl[24][12];

    if (t < 24) {
        float x = pose[b * 72 + t * 3 + 0];
        float y = pose[b * 72 + t * 3 + 1];
        float z = pose[b * 72 + t * 3 + 2];
        float th = sqrtf(x * x + y * y + z * z) + 1e-8f;
        float rx = x / th, ry = y / th, rz = z / th;
        float cs = cosf(th), sn = sinf(th), mc = 1.f - cs;
        float R[9];
        R[0] = cs + mc * rx * rx;      R[1] = mc * rx * ry - sn * rz; R[2] = mc * rx * rz + sn * ry;
        R[3] = mc * ry * rx + sn * rz; R[4] = cs + mc * ry * ry;      R[5] = mc * ry * rz - sn * rx;
        R[6] = mc * rz * rx - sn * ry; R[7] = mc * rz * ry + sn * rx; R[8] = cs + mc * rz * rz;
#pragma unroll
        for (int k = 0; k < 9; ++k) Rl[t][k] = R[k];
        if (t >= 1) {
#pragma unroll
            for (int k = 0; k < 9; ++k)
                lwX[b * 224 + (t - 1) * 9 + k] =
                    f2bf(R[k] - ((k == 0 || k == 4 || k == 8) ? 1.f : 0.f));
        }
#pragma unroll
        for (int c = 0; c < 3; ++c) {
            float a = js[(t * 3 + c) * 11 + 10];
#pragma unroll
            for (int s = 0; s < 10; ++s) a += betas[b * 10 + s] * js[(t * 3 + c) * 11 + s];
            Jl[t][c] = a;
        }
    } else if (t >= 32 && t < 42) {
        lwX[b * 224 + 207 + (t - 32)] = f2bf(betas[b * 10 + (t - 32)]);
    } else if (t == 42) {
        lwX[b * 224 + 217] = f2bf(1.f);
    } else if (t >= 43 && t < 49) {
        lwX[b * 224 + 218 + (t - 43)] = 0;
    }
    __syncthreads();

    if (t < 12) {
        int x = t >> 2, yy = t & 3;
        Gl[0][t] = (yy < 3) ? Rl[0][x * 3 + yy] : Jl[0][x];
    }
    __syncthreads();

    const int par[24] = {-1, 0, 0, 0, 1, 2, 3, 4, 5, 6, 7, 8, 9, 9, 9, 12, 13, 14, 16, 17, 18, 19, 20, 21};
#pragma unroll
    for (int i = 1; i < 24; ++i) {
        if (t < 12) {
            int x = t >> 2, yy = t & 3;
            int p = par[i];
            float a0, a1, a2, add;
            if (yy < 3) {
                a0 = Rl[i][0 * 3 + yy]; a1 = Rl[i][1 * 3 + yy]; a2 = Rl[i][2 * 3 + yy]; add = 0.f;
            } else {
                a0 = Jl[i][0] - Jl[p][0]; a1 = Jl[i][1] - Jl[p][1]; a2 = Jl[i][2] - Jl[p][2];
                add = Gl[p][x * 4 + 3];
            }
            Gl[i][t] = Gl[p][x * 4 + 0] * a0 + Gl[p][x * 4 + 1] * a1 + Gl[p][x * 4 + 2] * a2 + add;
        }
        __syncthreads();
    }

    // ga[r][b][j], r = x*4+y; translation adjusted (-G·J) and trans folded (sum_j w = 1)
    if (t < 24) {
#pragma unroll
        for (int x = 0; x < 3; ++x) {
            float tx = Gl[t][x * 4 + 0] * Jl[t][0] + Gl[t][x * 4 + 1] * Jl[t][1] + Gl[t][x * 4 + 2] * Jl[t][2];
#pragma unroll
            for (int yy = 0; yy < 3; ++yy)
                ga[(x * 4 + yy) * (512 * 32) + b * 32 + t] = f2bf(Gl[t][x * 4 + yy]);
            ga[(x * 4 + 3) * (512 * 32) + b * 32 + t] =
                f2bf(Gl[t][x * 4 + 3] - tx + trans[b * 3 + x]);
        }
    } else if (t < 32) {
#pragma unroll
        for (int r = 0; r < 12; ++r) ga[r * (512 * 32) + b * 32 + t] = 0;
    }
}

// ---------------- Kernel PE: PB[c][v][224] bf16 = posedirs | shapedirs | vt | 0
__global__ __launch_bounds__(256) void pe_kernel(const float* __restrict__ pd,
                                                 const float* __restrict__ sd,
                                                 const float* __restrict__ vt,
                                                 short* __restrict__ pb) {
    int v0 = blockIdx.x * 32;
    int c = blockIdx.y;
    int t = threadIdx.x;
    int vloc = t >> 3, sub = t & 7;
    int v = v0 + vloc;
    short* dst = pb + ((size_t)c * VPAD + v) * 224;
    if (v < VNUM) {
        const float* pr = pd + (size_t)v * 621 + c * 207;
        const float* sr = sd + (size_t)v * 30 + c * 10;
        float vtv = vt[v * 3 + c];
#pragma unroll
        for (int i = 0; i < 28; ++i) {
            int k = sub + i * 8;
            float val;
            if (k < 207) val = pr[k];
            else if (k < 217) val = sr[k - 207];
            else if (k == 217) val = vtv;
            else val = 0.f;
            dst[k] = f2bf(val);
        }
    } else {
#pragma unroll
        for (int i = 0; i < 28; ++i) dst[sub + i * 8] = 0;
    }
}

// ---------------- Kernel WP: Wt[v][32] bf16 = weights row, j-padded
__global__ __launch_bounds__(256) void wp_kernel(const float* __restrict__ w,
                                                 short* __restrict__ wt) {
    int v = blockIdx.x * 256 + threadIdx.x;
    if (v >= VPAD) return;
    short* dst = wt + (size_t)v * 32;
    if (v < VNUM) {
#pragma unroll
        for (int j = 0; j < 24; ++j) dst[j] = f2bf(w[(size_t)v * 24 + j]);
#pragma unroll
        for (int j = 24; j < 32; ++j) dst[j] = 0;
    } else {
#pragma unroll
        for (int j = 0; j < 32; ++j) dst[j] = 0;
    }
}

// ---------------- Kernel M: byte-exact R3 (validated) MFMA core + scattered store
// grid (16, 54): bx -> 32 batches, by -> 128 vertices (4 waves x 32 v)
__global__ __launch_bounds__(256) void km_kernel(const short* __restrict__ lwX,
                                                 const short* __restrict__ pb,
                                                 const short* __restrict__ ga,
                                                 const short* __restrict__ wt,
                                                 float* __restrict__ out) {
    int tid = threadIdx.x;
    int lane = tid & 63;
    int wid = tid >> 6;
    int row = lane & 15;
    int kq = lane >> 4;
    int b0 = blockIdx.x * 32;
    int v0 = blockIdx.y * 128 + wid * 32;

    f32x4 vp[2][2][3];  // [mrep][vb][c]
#pragma unroll
    for (int m = 0; m < 2; ++m)
#pragma unroll
        for (int vb = 0; vb < 2; ++vb)
#pragma unroll
            for (int c = 0; c < 3; ++c) vp[m][vb][c] = (f32x4){0.f, 0.f, 0.f, 0.f};

    // Phase 1: vp[b][v,c] = sum_k lwX[b][k] * PB[c][v][k], K = 224 (7 steps)
    const short* arow0 = lwX + (b0 + row) * 224 + kq * 8;
    const short* arow1 = arow0 + 16 * 224;
#pragma unroll
    for (int ks = 0; ks < 7; ++ks) {
        bf16x8 a0 = *(const bf16x8*)(arow0 + ks * 32);
        bf16x8 a1 = *(const bf16x8*)(arow1 + ks * 32);
#pragma unroll
        for (int vb = 0; vb < 2; ++vb) {
#pragma unroll
            for (int c = 0; c < 3; ++c) {
                bf16x8 bf = *(const bf16x8*)(pb + ((size_t)c * VPAD + v0 + vb * 16 + row) * 224 +
                                             ks * 32 + kq * 8);
                vp[0][vb][c] = __builtin_amdgcn_mfma_f32_16x16x32_bf16(a0, bf, vp[0][vb][c], 0, 0, 0);
                vp[1][vb][c] = __builtin_amdgcn_mfma_f32_16x16x32_bf16(a1, bf, vp[1][vb][c], 0, 0, 0);
            }
        }
    }

    // Phase 2: T_r[b][v] = sum_j G'A[r][b][j] * Wt[v][j]; res[x] = T_{x4+3} + sum_y T_{x4+y}*vp[y]
    bf16x8 wfrag[2];
#pragma unroll
    for (int vb = 0; vb < 2; ++vb)
        wfrag[vb] = *(const bf16x8*)(wt + (size_t)(v0 + vb * 16 + row) * 32 + kq * 8);

    const f32x4 zero4 = {0.f, 0.f, 0.f, 0.f};
    int brow = (lane >> 4) * 4;

#pragma unroll
    for (int x = 0; x < 3; ++x) {
        f32x4 res[2][2];
        // y = 3 (translation) first: res = T
        {
            int r = x * 4 + 3;
            bf16x8 g0 = *(const bf16x8*)(ga + ((size_t)r * 512 + b0 + row) * 32 + kq * 8);
            bf16x8 g1 = *(const bf16x8*)(ga + ((size_t)r * 512 + b0 + 16 + row) * 32 + kq * 8);
#pragma unroll
            for (int vb = 0; vb < 2; ++vb) {
                res[0][vb] = __builtin_amdgcn_mfma_f32_16x16x32_bf16(g0, wfrag[vb], zero4, 0, 0, 0);
                res[1][vb] = __builtin_amdgcn_mfma_f32_16x16x32_bf16(g1, wfrag[vb], zero4, 0, 0, 0);
            }
        }
#pragma unroll
        for (int y = 0; y < 3; ++y) {
            int r = x * 4 + y;
            bf16x8 g0 = *(const bf16x8*)(ga + ((size_t)r * 512 + b0 + row) * 32 + kq * 8);
            bf16x8 g1 = *(const bf16x8*)(ga + ((size_t)r * 512 + b0 + 16 + row) * 32 + kq * 8);
#pragma unroll
            for (int vb = 0; vb < 2; ++vb) {
                f32x4 t0 = __builtin_amdgcn_mfma_f32_16x16x32_bf16(g0, wfrag[vb], zero4, 0, 0, 0);
                f32x4 t1 = __builtin_amdgcn_mfma_f32_16x16x32_bf16(g1, wfrag[vb], zero4, 0, 0, 0);
#pragma unroll
                for (int reg = 0; reg < 4; ++reg) {
                    res[0][vb][reg] += t0[reg] * vp[0][vb][y][reg];
                    res[1][vb][reg] += t1[reg] * vp[1][vb][y][reg];
                }
            }
        }
        // store component x
#pragma unroll
        for (int m = 0; m < 2; ++m) {
#pragma unroll
            for (int vb = 0; vb < 2; ++vb) {
                int v = v0 + vb * 16 + row;
                if (v < VNUM) {
#pragma unroll
                    for (int reg = 0; reg < 4; ++reg) {
                        int b = b0 + m * 16 + brow + reg;
                        out[((size_t)b * VNUM + v) * 3 + x] = res[m][vb][reg];
                    }
                }
            }
        }
    }
}

// ---------------- Kernel D: joints[b,j,c] = sum_v jr2[j,v] * result[b,v,c]
__global__ __launch_bounds__(256) void kd_kernel(const float* __restrict__ res,
                                                 const float* __restrict__ jr2,
                                                 float* __restrict__ joints) {
    int b = blockIdx.x;
    int tid = threadIdx.x;
    float acc[24][3];
#pragma unroll
    for (int j = 0; j < 24; ++j)
#pragma unroll
        for (int c = 0; c < 3; ++c) acc[j][c] = 0.f;

    const float* rb = res + (size_t)b * VNUM * 3;
    for (int v = tid; v < VNUM; v += 256) {
        float r0 = rb[v * 3 + 0];
        float r1 = rb[v * 3 + 1];
        float r2 = rb[v * 3 + 2];
#pragma unroll
        for (int j = 0; j < 24; ++j) {
            float q = jr2[(size_t)j * VNUM + v];
            acc[j][0] += q * r0;
            acc[j][1] += q * r1;
            acc[j][2] += q * r2;
        }
    }
#pragma unroll
    for (int j = 0; j < 24; ++j)
#pragma unroll
        for (int c = 0; c < 3; ++c) {
            float a = acc[j][c];
#pragma unroll
            for (int off = 32; off >= 1; off >>= 1) a += __shfl_xor(a, off);
            acc[j][c] = a;
        }
    __shared__ float red[4][72];
    int lane = tid & 63, wid = tid >> 6;
    if (lane == 0) {
#pragma unroll
        for (int j = 0; j < 24; ++j)
#pragma unroll
            for (int c = 0; c < 3; ++c) red[wid][j * 3 + c] = acc[j][c];
    }
    __syncthreads();
    if (tid < 72)
        joints[(size_t)b * 72 + tid] = red[0][tid] + red[1][tid] + red[2][tid] + red[3][tid];
}

extern "C" void kernel_launch(void* const* d_in, const int* in_sizes, int n_in,
                              void* d_out, int out_size, void* d_ws, size_t ws_size,
                              hipStream_t stream) {
    const float* betas = (const float*)d_in[0];
    const float* pose = (const float*)d_in[1];
    const float* trans = (const float*)d_in[2];
    const float* v_template = (const float*)d_in[3];
    const float* shapedirs = (const float*)d_in[4];
    const float* posedirs = (const float*)d_in[5];
    const float* J_regressor = (const float*)d_in[6];
    const float* joint_regressor = (const float*)d_in[7];
    const float* weights = (const float*)d_in[8];
    float* out = (float*)d_out;

    float* wsf = (float*)d_ws;  // ~10.36 MB
    float* js = wsf + WS_JS;
    float* part = wsf + WS_PART;  // aliases pb start; pe overwrites AFTER ka2 reads (same stream)
    short* lwX = (short*)(wsf + WS_LWX);
    short* ga = (short*)(wsf + WS_GA);
    short* wt = (short*)(wsf + WS_WT);
    short* pb = (short*)(wsf + WS_PB);

    ka_kernel<<<dim3(24, 8), 256, 0, stream>>>(J_regressor, shapedirs, v_template, part);
    ka2_kernel<<<24, 64, 0, stream>>>(part, js);
    pe_kernel<<<dim3(216, 3), 256, 0, stream>>>(posedirs, shapedirs, v_template, pb);
    wp_kernel<<<27, 256, 0, stream>>>(weights, wt);
    kb_kernel<<<512, 64, 0, stream>>>(pose, betas, trans, js, lwX, ga);
    km_kernel<<<dim3(16, 54), 256, 0, stream>>>(lwX, pb, ga, wt, out);
    kd_kernel<<<512, 256, 0, stream>>>(out, joint_regressor, out + RES_ELEMS);
}